// Round 2
// 403.539 us; speedup vs baseline: 1.0343x; 1.0343x over previous
//
#include <hip/hip_runtime.h>
#include <hip/hip_bf16.h>
#include <cstdint>
#include <cstddef>

// ---------------------------------------------------------------------------
// DatastoreReaderLayer: S=256 B=4 D=512 N=32768, TEMP=0.5
// Math restructured:
//   q1 = (q @ Wq^T + bq) * D^-0.5                      [1024,512] fp32
//   Q2 = (q1 @ Wk) * (1/TEMP)  (bf16)   cq = (q1.bk)*(1/TEMP)
//   E[q,n] = exp(Q2[q,:].k_raw[n,:] + cq[q])  (no max-sub; logits ~N(0,1))
//   racc = E @ V_raw (fp32, split-N atomics), l = rowsum(E)
//   attn = (racc/l) @ Wv^T + bv
//   h = relu([attn|prev] @ Wg1^T + bg1); s = sigmoid(h.wg2 + bg2)
//   out = attn*s + prev*(1-s)        (row index qi = s*B+b == input layout!)
// WS BUDGET: needs ws_size >= 74,457,088 bytes (kbf 32MB, vt 32MB, rest ~9MB)
//
// R1 flash restructure (resubmit R2 — R1 bench was an infra failure):
//  - deferred-PV 2-barrier pipeline (Es double-buffered): logits(sub) and
//    PV(sub-1) share one inter-barrier region -> 32 MFMA back-to-back
//  - XCD-aware block remap: XCD x owns ch {2x,2x+1} so the 16 blocks sharing
//    a K/V chunk co-reside on one XCD's L2
//  - global prefetch issued at region start (K 1 sub ahead, V ping-pong)
//  - s_setprio(1) around MFMA cluster
// ---------------------------------------------------------------------------

typedef unsigned short u16;
typedef u16    u16x8 __attribute__((ext_vector_type(8)));
typedef u16    u16x4 __attribute__((ext_vector_type(4)));
typedef __bf16 bf16x8 __attribute__((ext_vector_type(8)));
typedef float  f32x4 __attribute__((ext_vector_type(4)));

#define MFMA16(a, b, c) __builtin_amdgcn_mfma_f32_16x16x32_bf16( \
    __builtin_bit_cast(bf16x8, (a)), __builtin_bit_cast(bf16x8, (b)), (c), 0, 0, 0)

__device__ __forceinline__ u16 f2bf(float f) {  // RNE float->bf16
  unsigned u = __builtin_bit_cast(unsigned, f);
  u += 0x7fffu + ((u >> 16) & 1u);
  return (u16)(u >> 16);
}

// ------------------------- prep: dstore_k -> bf16 ---------------------------
__global__ __launch_bounds__(256) void prep_cvt(const float* __restrict__ src,
                                                u16* __restrict__ dst) {
  size_t i = ((size_t)blockIdx.x * 256 + threadIdx.x) * 4;
  float4 v = *(const float4*)(src + i);
  u16x4 o = {f2bf(v.x), f2bf(v.y), f2bf(v.z), f2bf(v.w)};
  *(u16x4*)(dst + i) = o;
}

// --------------- prep: dstore_v -> bf16 transposed [512][32768] -------------
__global__ __launch_bounds__(256) void prep_vt(const float* __restrict__ v,
                                               u16* __restrict__ vt) {
  __shared__ u16 Lt[64 * 72];  // [d_local][n_local+pad]
  const int n0 = blockIdx.x * 64, d0 = blockIdx.y * 64;
  const int t = threadIdx.x;
  const int n = t >> 2, c4 = t & 3;
#pragma unroll
  for (int i = 0; i < 4; i++) {
    int col = (c4 + 4 * i) * 4;
    float4 x = *(const float4*)(v + (size_t)(n0 + n) * 512 + d0 + col);
    Lt[(col + 0) * 72 + n] = f2bf(x.x);
    Lt[(col + 1) * 72 + n] = f2bf(x.y);
    Lt[(col + 2) * 72 + n] = f2bf(x.z);
    Lt[(col + 3) * 72 + n] = f2bf(x.w);
  }
  __syncthreads();
#pragma unroll
  for (int u = 0; u < 2; u++) {
    int unit = t + 256 * u;  // 512 units: 64 d-rows x 8 units of 8 ushorts
    int d = unit >> 3, un = unit & 7;
    *(u16x8*)(vt + (size_t)(d0 + d) * 32768 + n0 + un * 8) =
        *(const u16x8*)&Lt[d * 72 + un * 8];
  }
}

// ---------------- small MFMA GEMM: C = act((A @ op(B) + bias)*alpha) --------
// A [M,K] fp32 row-major (CONCAT: A cols 0..511, A2 cols 512..1023, lda=512)
// TRANSB: B [N,K] (use B rows);  !TRANSB: B [K,N]
// ROWSCALE: A row r scaled by 1/lvec[r] during staging
template <bool TRANSB, bool CONCAT, bool RELU, bool OUTBF16, bool ROWSCALE>
__global__ __launch_bounds__(256, 2) void gemm64(
    const float* __restrict__ A, const float* __restrict__ A2,
    const float* __restrict__ B, const float* __restrict__ bias,
    const float* __restrict__ lvec, float alpha, void* __restrict__ Cv,
    int M, int N, int K) {
  __shared__ u16 As[64 * 72];
  __shared__ u16 Bs[64 * 72];  // [n_local][k_local]
  const int tid = threadIdx.x;
  const int w = tid >> 6, lane = tid & 63, quad = lane >> 4, l15 = lane & 15;
  const int m0 = blockIdx.y * 64, n0 = blockIdx.x * 64;
  const int arow = tid >> 2, ac4 = tid & 3;
  float rs = 1.0f;
  if (ROWSCALE) rs = 1.0f / lvec[m0 + arow];
  const f32x4 fzero = {0.f, 0.f, 0.f, 0.f};
  f32x4 acc[4];
#pragma unroll
  for (int i = 0; i < 4; i++) acc[i] = fzero;

  for (int k0 = 0; k0 < K; k0 += 64) {
    __syncthreads();
    {  // stage A tile (row-major [m][k], bf16)
      const float* src;
      if (CONCAT)
        src = (k0 < 512) ? (A + (size_t)(m0 + arow) * 512 + k0)
                         : (A2 + (size_t)(m0 + arow) * 512 + (k0 - 512));
      else
        src = A + (size_t)(m0 + arow) * K + k0;
#pragma unroll
      for (int i = 0; i < 4; i++) {
        int col = (ac4 + 4 * i) * 4;
        float4 x = *(const float4*)(src + col);
        if (ROWSCALE) { x.x *= rs; x.y *= rs; x.z *= rs; x.w *= rs; }
        u16x4 o = {f2bf(x.x), f2bf(x.y), f2bf(x.z), f2bf(x.w)};
        *(u16x4*)&As[arow * 72 + col] = o;
      }
    }
    if (TRANSB) {  // B [N,K]: rows are n -> same staging pattern
      const float* src = B + (size_t)(n0 + arow) * K + k0;
#pragma unroll
      for (int i = 0; i < 4; i++) {
        int col = (ac4 + 4 * i) * 4;
        float4 x = *(const float4*)(src + col);
        u16x4 o = {f2bf(x.x), f2bf(x.y), f2bf(x.z), f2bf(x.w)};
        *(u16x4*)&Bs[arow * 72 + col] = o;
      }
    } else {  // B [K,N]: transpose into Bs[n][k]
      const float* src = B + (size_t)(k0 + arow) * N + n0;
#pragma unroll
      for (int i = 0; i < 4; i++) {
        int col = (ac4 + 4 * i) * 4;
        float4 x = *(const float4*)(src + col);
        Bs[(col + 0) * 72 + arow] = f2bf(x.x);
        Bs[(col + 1) * 72 + arow] = f2bf(x.y);
        Bs[(col + 2) * 72 + arow] = f2bf(x.z);
        Bs[(col + 3) * 72 + arow] = f2bf(x.w);
      }
    }
    __syncthreads();
#pragma unroll
    for (int ks = 0; ks < 2; ks++) {
      u16x8 af = *(const u16x8*)&As[(w * 16 + l15) * 72 + ks * 32 + quad * 8];
#pragma unroll
      for (int nt = 0; nt < 4; nt++) {
        u16x8 bf = *(const u16x8*)&Bs[(nt * 16 + l15) * 72 + ks * 32 + quad * 8];
        acc[nt] = MFMA16(af, bf, acc[nt]);
      }
    }
  }
#pragma unroll
  for (int nt = 0; nt < 4; nt++) {
    int col = n0 + nt * 16 + l15;
    float b = bias ? bias[col] : 0.f;
#pragma unroll
    for (int i = 0; i < 4; i++) {
      int row = m0 + w * 16 + quad * 4 + i;
      float y = (acc[nt][i] + b) * alpha;
      if (RELU) y = fmaxf(y, 0.f);
      if (OUTBF16)
        ((u16*)Cv)[(size_t)row * N + col] = f2bf(y);
      else
        ((float*)Cv)[(size_t)row * N + col] = y;
    }
  }
}

// ----------------------------- cq = 2*(q1 . bk) -----------------------------
__global__ void cq_kernel(const float* __restrict__ q1,
                          const float* __restrict__ bk,
                          float* __restrict__ cq) {
  int r = blockIdx.x, lane = threadIdx.x;  // 64 threads = 1 wave
  float s = 0.f;
#pragma unroll
  for (int k = 0; k < 512; k += 64) s += q1[(size_t)r * 512 + k + lane] * bk[k + lane];
#pragma unroll
  for (int off = 32; off; off >>= 1) s += __shfl_down(s, off, 64);
  if (lane == 0) cq[r] = 2.0f * s;
}

// ------------------------------- flash kernel -------------------------------
// grid 256, 8 waves. XCD-aware remap: x=bx&7 (XCD), j=bx>>3;
//   ch = 2x+(j&1) (2048 n-rows), qt = j>>1 (64 queries).
// wave w: logits rows qg=w>>1 (16q) x n-half nh=w&1 (16n of 32);
//         PV: all 64q x cols [w*64, w*64+64).
// Pipeline per sub (2 barriers): [A; stage Ks; B; issue K/V prefetch;
//   logits(sub) + PV(sub-1) fused; exp -> Es[sub&1]]
__global__ __launch_bounds__(512, 2) void flash(
    const u16* __restrict__ kbf,  // [32768][512] bf16
    const u16* __restrict__ vt,   // [512][32768] bf16 (transposed V)
    const u16* __restrict__ q2,   // [1024][512] bf16 (scaled 2*(q1@Wk))
    const float* __restrict__ cq, // [1024]
    float* __restrict__ racc,     // [1024][512] fp32, pre-zeroed
    float* __restrict__ lacc) {   // [1024] fp32, pre-zeroed
  __shared__ u16 Ks[32 * 520];    // [n_local][d+pad]
  __shared__ u16 Es[2][64 * 40];  // double-buffered [q_local][n_local+pad]
  const int tid = threadIdx.x;
  const int w = tid >> 6, lane = tid & 63, quad = lane >> 4, l15 = lane & 15;
  // XCD-aware remap: blocks with bx%8==x land on XCD x; give XCD x chunks
  // {2x, 2x+1} so all 16 blocks sharing a K/V chunk share one L2.
  const int x = blockIdx.x & 7, j = blockIdx.x >> 3;
  const int ch = 2 * x + (j & 1), qt = j >> 1;
  const int qbase = qt * 64;
  const int qg = w >> 1, nh = w & 1;
  const int colb = w * 64;
  const int nbase = ch * 2048;

  // Q fragments: 16 x (16q x 32d) in registers (64 VGPRs)
  u16x8 qf[16];
  {
    const u16* qp = q2 + (size_t)(qbase + qg * 16 + l15) * 512 + quad * 8;
#pragma unroll
    for (int ks = 0; ks < 16; ks++) qf[ks] = *(const u16x8*)(qp + ks * 32);
  }
  float cq4[4];
#pragma unroll
  for (int i = 0; i < 4; i++) cq4[i] = cq[qbase + qg * 16 + quad * 4 + i];
  float lp[4] = {0.f, 0.f, 0.f, 0.f};
  const f32x4 fzero = {0.f, 0.f, 0.f, 0.f};
  f32x4 acc[4][4];
#pragma unroll
  for (int a = 0; a < 4; a++)
#pragma unroll
    for (int b = 0; b < 4; b++) acc[a][b] = fzero;

  u16x8 st[4];          // K-subtile staging regs (1 sub ahead)
  u16x8 bvA[4], bvB[4]; // V fragments, ping-pong (consumed 1 sub later)

#define STORE_KS()                                                      \
  {                                                                     \
    _Pragma("unroll") for (int u = 0; u < 4; u++) {                     \
      int flat = tid + u * 512;                                         \
      *(u16x8*)&Ks[(flat >> 6) * 520 + (flat & 63) * 8] = st[u];        \
    }                                                                   \
  }
#define LOAD_K(SUBN)                                                    \
  {                                                                     \
    _Pragma("unroll") for (int u = 0; u < 4; u++) {                     \
      int flat = tid + u * 512;                                         \
      st[u] = *(const u16x8*)(kbf +                                     \
          (size_t)(nbase + (SUBN) * 32 + (flat >> 6)) * 512 +           \
          (flat & 63) * 8);                                             \
    }                                                                   \
  }
#define LOAD_V(BV, SUBN)                                                \
  {                                                                     \
    _Pragma("unroll") for (int ct = 0; ct < 4; ct++)                    \
      BV[ct] = *(const u16x8*)(vt +                                     \
          (size_t)(colb + ct * 16 + l15) * 32768 +                      \
          nbase + (SUBN) * 32 + quad * 8);                              \
  }
#define LOGITS(SV)                                                      \
  {                                                                     \
    _Pragma("unroll") for (int ks = 0; ks < 16; ks++) {                 \
      u16x8 bfg = *(const u16x8*)&Ks[(nh * 16 + l15) * 520 + ks * 32 +  \
                                     quad * 8];                         \
      SV = MFMA16(qf[ks], bfg, SV);                                     \
    }                                                                   \
  }
#define PV_STEP(ER, BV)                                                 \
  {                                                                     \
    u16x8 ef[4];                                                        \
    _Pragma("unroll") for (int q2i = 0; q2i < 4; q2i++)                 \
      ef[q2i] = *(const u16x8*)&(ER)[(q2i * 16 + l15) * 40 + quad * 8]; \
    _Pragma("unroll") for (int ct = 0; ct < 4; ct++)                    \
      _Pragma("unroll") for (int q2i = 0; q2i < 4; q2i++)               \
        acc[q2i][ct] = MFMA16(ef[q2i], BV[ct], acc[q2i][ct]);           \
  }
#define EXPW(EW, SV)                                                    \
  {                                                                     \
    _Pragma("unroll") for (int i = 0; i < 4; i++) {                     \
      float e = __expf(SV[i] + cq4[i]);                                 \
      lp[i] += e;                                                       \
      (EW)[(qg * 16 + quad * 4 + i) * 40 + nh * 16 + l15] = f2bf(e);    \
    }                                                                   \
  }

  // ---- prologue: sub 0 (no PV yet) ----
  LOAD_K(0);
  STORE_KS();
  __syncthreads();  // B: Ks staged
  LOAD_K(1);
  LOAD_V(bvA, 0);
  {
    f32x4 s = fzero;
    LOGITS(s);
    EXPW(Es[0], s);
  }

  // ---- main: subs 1..62 in explicit odd/even pairs ----
#pragma unroll 1
  for (int sb = 1; sb < 63; sb += 2) {
    // sub = sb (odd): write Es[1], PV reads Es[0] (sub-1), V from bvA
    __syncthreads();  // A: prev logits reads done -> Ks free
    STORE_KS();
    __syncthreads();  // B: Ks staged, prev Es writes published
    LOAD_K(sb + 1);
    LOAD_V(bvB, sb);
    __builtin_amdgcn_s_setprio(1);
    f32x4 s = fzero;
    LOGITS(s);
    PV_STEP(Es[0], bvA);
    __builtin_amdgcn_s_setprio(0);
    EXPW(Es[1], s);
    // sub = sb+1 (even): write Es[0], PV reads Es[1], V from bvB
    __syncthreads();  // A
    STORE_KS();
    __syncthreads();  // B
    LOAD_K(sb + 2);
    LOAD_V(bvA, sb + 1);
    __builtin_amdgcn_s_setprio(1);
    f32x4 t = fzero;
    LOGITS(t);
    PV_STEP(Es[1], bvB);
    __builtin_amdgcn_s_setprio(0);
    EXPW(Es[0], t);
  }

  // ---- sub 63 (odd, no K prefetch) ----
  __syncthreads();  // A
  STORE_KS();
  __syncthreads();  // B
  LOAD_V(bvB, 63);
  {
    __builtin_amdgcn_s_setprio(1);
    f32x4 s = fzero;
    LOGITS(s);
    PV_STEP(Es[0], bvA);
    __builtin_amdgcn_s_setprio(0);
    EXPW(Es[1], s);
  }
  // ---- epilogue: PV for sub 63 ----
  __syncthreads();
  PV_STEP(Es[1], bvB);

#undef STORE_KS
#undef LOAD_K
#undef LOAD_V
#undef LOGITS
#undef PV_STEP
#undef EXPW

  // combine partials across the 16 N-chunks
#pragma unroll
  for (int q2i = 0; q2i < 4; q2i++)
#pragma unroll
    for (int ct = 0; ct < 4; ct++) {
      int col = colb + ct * 16 + l15;
#pragma unroll
      for (int i = 0; i < 4; i++) {
        int row = qbase + q2i * 16 + quad * 4 + i;
        atomicAdd(&racc[(size_t)row * 512 + col], acc[q2i][ct][i]);
      }
    }
#pragma unroll
  for (int i = 0; i < 4; i++) {
    float v = lp[i];
#pragma unroll
    for (int off = 1; off < 16; off <<= 1) v += __shfl_xor(v, off, 64);
    if (l15 == 0) atomicAdd(&lacc[qbase + qg * 16 + quad * 4 + i], v);
  }
}

// ----------------------- finalize: sigma gate + mix -------------------------
__global__ __launch_bounds__(256) void finalize(
    const float* __restrict__ h, const float* __restrict__ attn,
    const float* __restrict__ prev, const float* __restrict__ wg2,
    const float* __restrict__ bg2, float* __restrict__ out) {
  __shared__ float red[4];
  int r = blockIdx.x, t = threadIdx.x;
  const float* hr = h + (size_t)r * 512;
  float p = hr[t] * wg2[t] + hr[t + 256] * wg2[t + 256];
#pragma unroll
  for (int off = 32; off; off >>= 1) p += __shfl_down(p, off, 64);
  if ((t & 63) == 0) red[t >> 6] = p;
  __syncthreads();
  float dot = red[0] + red[1] + red[2] + red[3];
  float sg = 1.f / (1.f + __expf(-(dot + bg2[0])));
  size_t base = (size_t)r * 512;
  out[base + t] = attn[base + t] * sg + prev[base + t] * (1.f - sg);
  out[base + t + 256] = attn[base + t + 256] * sg + prev[base + t + 256] * (1.f - sg);
}

// ---------------------------------------------------------------------------
extern "C" void kernel_launch(void* const* d_in, const int* in_sizes, int n_in,
                              void* d_out, int out_size, void* d_ws, size_t ws_size,
                              hipStream_t stream) {
  const float* q    = (const float*)d_in[0];
  const float* prev = (const float*)d_in[1];
  const float* Wq   = (const float*)d_in[2];
  const float* bq   = (const float*)d_in[3];
  const float* Wk   = (const float*)d_in[4];
  const float* bk   = (const float*)d_in[5];
  const float* Wv   = (const float*)d_in[6];
  const float* bv   = (const float*)d_in[7];
  const float* Wg1  = (const float*)d_in[8];
  const float* bg1  = (const float*)d_in[9];
  const float* Wg2  = (const float*)d_in[10];
  const float* bg2  = (const float*)d_in[11];
  const float* dk   = (const float*)d_in[12];
  const float* dv   = (const float*)d_in[13];
  float* out = (float*)d_out;

  char* ws = (char*)d_ws;
  u16*   kbf  = (u16*)(ws);                  // 33,554,432 B
  u16*   vt   = (u16*)(ws + 33554432);       // 33,554,432 B
  float* racc = (float*)(ws + 67108864);     // 2 MB
  float* lacc = (float*)(ws + 69206016);     // 4 KB (contiguous after racc)
  float* cqv  = (float*)(ws + 69210112);     // 4 KB
  u16*   q2   = (u16*)(ws + 69214208);       // 1 MB
  float* q1   = (float*)(ws + 70262784);     // 2 MB (reused as h)
  float* attn = (float*)(ws + 72359936);     // 2 MB   -> total 74,457,088 B
  float* h    = q1;

  prep_cvt<<<16384, 256, 0, stream>>>(dk, kbf);
  prep_vt<<<dim3(512, 8), 256, 0, stream>>>(dv, vt);
  // q1 = (q @ Wq^T + bq) * D^-0.5
  gemm64<true, false, false, false, false><<<dim3(8, 16), 256, 0, stream>>>(
      q, nullptr, Wq, bq, nullptr, 0.044194173824159216f, q1, 1024, 512, 512);
  cq_kernel<<<1024, 64, 0, stream>>>(q1, bk, cqv);
  // Q2 = (q1 @ Wk) * 2   (bf16)
  gemm64<false, false, false, true, false><<<dim3(8, 16), 256, 0, stream>>>(
      q1, nullptr, Wk, nullptr, nullptr, 2.0f, q2, 1024, 512, 512);
  hipMemsetAsync(racc, 0, 2097152 + 4096, stream);  // racc + lacc
  flash<<<256, 512, 0, stream>>>(kbf, vt, q2, cqv, racc, lacc);
  // attn = (racc/l) @ Wv^T + bv
  gemm64<true, false, false, false, true><<<dim3(8, 16), 256, 0, stream>>>(
      racc, nullptr, Wv, bv, lacc, 1.0f, attn, 1024, 512, 512);
  // h = relu([attn|prev] @ Wg1^T + bg1)
  gemm64<true, true, true, false, false><<<dim3(8, 16), 256, 0, stream>>>(
      attn, prev, Wg1, bg1, nullptr, 1.0f, h, 1024, 512, 1024);
  finalize<<<1024, 256, 0, stream>>>(h, attn, prev, Wg2, bg2, out);
}